// Round 4
// baseline (524.062 us; speedup 1.0000x reference)
//
#include <hip/hip_runtime.h>
#include <math.h>

#define Hh 24
#define Ww 24
#define Nn 576
#define Dd 1024
#define Bb 32
#define Kk 256
#define Mm 128
#define TOKSTRIDE (577 * 1024)

// Per-batch scratch lives INSIDE d_out: batch b owns out[b*Mm*Dd .. (b+1)*Mm*Dd).
// Scratch is consumed (via LDS/regs) before the plan/output phases overwrite
// the rows. d_ws is NOT used.
#define R0_OFF 0       // roots0           : 576 int
#define P_OFF 2944     // p = patch.u      : 576 float
#define QC_OFF 3776    // qcls             : 1024 float
#define U_OFF 4800     // u = qcls.v_w     : 1024 float
#define T_OFF 5824     // t = qcls.v_b     : 1 float

__device__ __forceinline__ float* batch_base(float* out, int b) {
  return out + (size_t)b * Mm * Dd;
}

// Full-wave (64-lane) float sum via DPP — VALU pipe only, no LDS traffic.
// Canonical gfx9/CDNA sequence; result valid in lane 63.
__device__ __forceinline__ float wave_sum_dpp(float x) {
  int y;
  y = __builtin_amdgcn_update_dpp(0, __float_as_int(x), 0x111, 0xf, 0xf, true);
  x += __int_as_float(y);  // row_shr:1
  y = __builtin_amdgcn_update_dpp(0, __float_as_int(x), 0x112, 0xf, 0xf, true);
  x += __int_as_float(y);  // row_shr:2
  y = __builtin_amdgcn_update_dpp(0, __float_as_int(x), 0x114, 0xf, 0xf, true);
  x += __int_as_float(y);  // row_shr:4
  y = __builtin_amdgcn_update_dpp(0, __float_as_int(x), 0x118, 0xf, 0xf, true);
  x += __int_as_float(y);  // row_shr:8  -> lanes 15/31/47/63 hold row sums
  y = __builtin_amdgcn_update_dpp(0, __float_as_int(x), 0x142, 0xa, 0xf, true);
  x += __int_as_float(y);  // row_bcast:15 into rows 1,3
  y = __builtin_amdgcn_update_dpp(0, __float_as_int(x), 0x143, 0xc, 0xf, true);
  x += __int_as_float(y);  // row_bcast:31 into rows 2,3 -> lane 63 = total
  return x;
}

// 16-lane row sum via DPP (4 stages). Lanes 15/31/47/63 hold their row's sum.
__device__ __forceinline__ float row_sum_dpp(float x) {
  int y;
  y = __builtin_amdgcn_update_dpp(0, __float_as_int(x), 0x111, 0xf, 0xf, true);
  x += __int_as_float(y);  // row_shr:1
  y = __builtin_amdgcn_update_dpp(0, __float_as_int(x), 0x112, 0xf, 0xf, true);
  x += __int_as_float(y);  // row_shr:2
  y = __builtin_amdgcn_update_dpp(0, __float_as_int(x), 0x114, 0xf, 0xf, true);
  x += __int_as_float(y);  // row_shr:4
  y = __builtin_amdgcn_update_dpp(0, __float_as_int(x), 0x118, 0xf, 0xf, true);
  x += __int_as_float(y);  // row_shr:8
  return x;
}

// ---------------------------------------------------------------------------
// K4 (runs FIRST): qcls[b,dp] = cls[b]·q_w[dp,:] + q_b[dp]. One block per dp;
//     4 waves, each handles 8 batches (q_w row reused in regs).
// ---------------------------------------------------------------------------
__global__ __launch_bounds__(256) void qcls_kernel(
    const float* __restrict__ tok2d, const float* __restrict__ q_w,
    const float* __restrict__ q_b, float* __restrict__ outb) {
  int dp = blockIdx.x;
  int wave = threadIdx.x >> 6;
  int lane = threadIdx.x & 63;
  float4 qv[4];
#pragma unroll
  for (int i = 0; i < 4; i++)
    qv[i] = *(const float4*)(q_w + (size_t)dp * Dd + lane * 4 + 256 * i);
  float qb = q_b[dp];
  for (int bb = 0; bb < 8; bb++) {
    int b = wave * 8 + bb;
    const float* cls = tok2d + (size_t)b * TOKSTRIDE;
    float a = 0.f;
#pragma unroll
    for (int i = 0; i < 4; i++) {
      float4 cv = *(const float4*)(cls + lane * 4 + 256 * i);
      a += qv[i].x * cv.x + qv[i].y * cv.y + qv[i].z * cv.z + qv[i].w * cv.w;
    }
    a = wave_sum_dpp(a);
    if (lane == 63) batch_base(outb, b)[QC_OFF + dp] = a + qb;
  }
}

// ---------------------------------------------------------------------------
// K5' (fused u_part + combine_ut): u[b][d] = sum_dp qcls[b][dp]*v_w[dp][d],
//     t[b] = qcls[b]·v_b. Grid 32 = bgroup(8) x dslice(4). Each block: 4
//     batches share every v_w float4 (qcls for the group staged in LDS) ->
//     v_w global traffic drops 128 MB -> 32 MB/iter. No chunk partials,
//     no second kernel. Wave w = batch bi (lanes uniform in bi) so the
//     t-reduction is a clean full-wave DPP.
// ---------------------------------------------------------------------------
__global__ __launch_bounds__(256) void u_t_kernel(const float* __restrict__ v_w,
                                                  const float* __restrict__ v_b,
                                                  float* __restrict__ outb) {
  int bg = blockIdx.x >> 2;  // batch group 0..7
  int ds = blockIdx.x & 3;   // d-slice 0..3 (256 d's each)
  int bi = threadIdx.x >> 6; // batch within group 0..3 (= wave)
  int col = threadIdx.x & 63;
  int b = bg * 4 + bi;
  int d0 = ds * 256 + col * 4;
  __shared__ float qs[4][Dd];
  for (int i = threadIdx.x; i < 4 * Dd; i += 256) {
    int bb = i >> 10;
    qs[bb][i & 1023] = batch_base(outb, bg * 4 + bb)[QC_OFF + (i & 1023)];
  }
  __syncthreads();
  float4 a = make_float4(0.f, 0.f, 0.f, 0.f);
#pragma unroll 4
  for (int dp = 0; dp < Dd; dp++) {
    float4 vv = *(const float4*)(v_w + (size_t)dp * Dd + d0);
    float qq = qs[bi][dp];
    a.x += qq * vv.x; a.y += qq * vv.y; a.z += qq * vv.z; a.w += qq * vv.w;
  }
  *(float4*)(batch_base(outb, b) + U_OFF + d0) = a;

  if (ds == 0) {  // t for this block's 4 batches, one wave each
    float s = 0.f;
    for (int i = col; i < Dd; i += 64) s += qs[bi][i] * v_b[i];
    s = wave_sum_dpp(s);
    if (col == 63) batch_base(outb, b)[T_OFF] = s;
  }
}

// ---------------------------------------------------------------------------
// K1 v5: fused affinity + p. Block = (b, y, octet of 8 x's); 4 waves = 4
//     d-chunks of 256. Row-major sliding-window conv (3 rows x 10 cols, 30
//     float4 loads/thread); dw(36f)+pw(36f) register-resident in two phases
//     split by sched_barrier. The p partial (center·u) is DPP-reduced and
//     retired to red[][9] AT CONV TIME (ky==1) — pacc[] and u4 die before
//     the pointwise phase, shrinking the cross-phase live set (round-3
//     counters showed an 8 B/thread scratch spill from that live range).
//     __launch_bounds__(256,8): lock the 64-VGPR / 8-waves-per-EU point the
//     allocator already chose in round 3.
//     Reduction: 4-stage DPP 16-lane row sums -> 16 partials/(t,o) in padded
//     LDS; finalize 2 lanes x 4 waves, fixed r-order (bitwise stable).
//     XCD-bijective block swizzle (2304 = 8*288): contiguous (b,y) per XCD.
// ---------------------------------------------------------------------------
__global__ __launch_bounds__(256, 8) void affinity_p_root_kernel(
    const float* __restrict__ tok2d, const float* __restrict__ dw_w,
    const float* __restrict__ pw_w, const float* __restrict__ pw_b,
    float* __restrict__ outb) {
  int wave = threadIdx.x >> 6;  // d-chunk
  int lane = threadIdx.x & 63;
  // XCD-aware bijective swizzle: 2304 blocks = 8 XCDs * 288 contiguous ids.
  int blk = (blockIdx.x & 7) * (Bb * Hh * 3 / 8) + (blockIdx.x >> 3);
  int b = blk / (Hh * 3);
  int rem = blk % (Hh * 3);
  int y = rem / 3;
  int x0 = (rem % 3) * 8;
  int d0 = wave * 256 + lane * 4;
  const float* patch = tok2d + (size_t)b * TOKSTRIDE + Dd;  // skip cls token
  float* basef = batch_base(outb, b);

  // red layout: [t:0..7][r:0..15][o:0..9], linear idx = t*167 + r*10 + o.
  // 167 (odd, %32==7) pads the t-stride so finalizer lanes don't collide.
  __shared__ float red[8 * 167 + 8];

  // conv-phase registers: depthwise weights (36f) + u (4f)
  union { float4 v[9]; float f[36]; } w;
  const float4* dwp = (const float4*)(dw_w + (size_t)d0 * 9);
#pragma unroll
  for (int j = 0; j < 9; j++) w.v[j] = dwp[j];
  float4 u4 = *(const float4*)(basef + U_OFF + d0);

  // --- depthwise conv: sliding window over 3 rows x 10 cols.
  //     p partial is reduced and retired to LDS inline at ky==1. ---
  float4 cc[8];
#pragma unroll
  for (int t = 0; t < 8; t++) cc[t] = make_float4(0.f, 0.f, 0.f, 0.f);
#pragma unroll
  for (int ky = 0; ky < 3; ky++) {
    int yy = y + ky - 1;
    if (yy < 0 || yy >= Hh) continue;  // wave-uniform (zero padding)
    const float* prow = patch + (size_t)(yy * Ww) * Dd + d0;
    float4 wA = make_float4(0.f, 0.f, 0.f, 0.f);
    if (x0 > 0) wA = *(const float4*)(prow + (size_t)(x0 - 1) * Dd);
    float4 wB = *(const float4*)(prow + (size_t)x0 * Dd);
    int kA = ky * 3, kB = ky * 3 + 1, kC = ky * 3 + 2;
#pragma unroll
    for (int t = 0; t < 8; t++) {
      float4 wC = make_float4(0.f, 0.f, 0.f, 0.f);
      int xx = x0 + t + 1;
      if (xx < Ww) wC = *(const float4*)(prow + (size_t)xx * Dd);
      cc[t].x += wA.x * w.f[kA] + wB.x * w.f[kB] + wC.x * w.f[kC];
      cc[t].y += wA.y * w.f[9 + kA] + wB.y * w.f[9 + kB] + wC.y * w.f[9 + kC];
      cc[t].z += wA.z * w.f[18 + kA] + wB.z * w.f[18 + kB] + wC.z * w.f[18 + kC];
      cc[t].w += wA.w * w.f[27 + kA] + wB.w * w.f[27 + kB] + wC.w * w.f[27 + kC];
      if (ky == 1) {  // middle row: wB is token t's center -> p, reduced now
        float pa = wB.x * u4.x + wB.y * u4.y + wB.z * u4.z + wB.w * u4.w;
        pa = row_sum_dpp(pa);
        if ((lane & 15) == 15)
          red[t * 167 + (wave * 4 + (lane >> 4)) * 10 + 9] = pa;
      }
      wA = wB;
      wB = wC;
    }
  }

  // fence: keep pw loads out of the conv region (two-phase VGPR liveness)
  __builtin_amdgcn_sched_barrier(0);

  // pointwise-phase registers: pw (36f); dw/u now dead
  float4 pw[9];
#pragma unroll
  for (int o = 0; o < 9; o++)
    pw[o] = *(const float4*)(pw_w + (size_t)o * Dd + d0);

  // --- per-token pointwise logits + 4-stage DPP row reduction ---
#pragma unroll
  for (int t = 0; t < 8; t++) {
    float acc[9];
#pragma unroll
    for (int o = 0; o < 9; o++) {
      acc[o] = cc[t].x * pw[o].x + cc[t].y * pw[o].y + cc[t].z * pw[o].z +
               cc[t].w * pw[o].w;
    }
#pragma unroll
    for (int o = 0; o < 9; o++) acc[o] = row_sum_dpp(acc[o]);
    if ((lane & 15) == 15) {
      int r = wave * 4 + (lane >> 4);
#pragma unroll
      for (int o = 0; o < 9; o++) red[t * 167 + r * 10 + o] = acc[o];
    }
  }
  __syncthreads();

  // --- finalize: 2 lanes per wave, token t = wave*2 + lane ---
  if (lane < 2) {
    int t = wave * 2 + lane;
    int x = x0 + t;
    int n = y * Ww + x;
    float l[10];
#pragma unroll
    for (int o = 0; o < 10; o++) l[o] = 0.f;
    for (int r = 0; r < 16; r++) {
#pragma unroll
      for (int o = 0; o < 10; o++) l[o] += red[t * 167 + r * 10 + o];
    }
    float q[9];
    float mx = -INFINITY;
#pragma unroll
    for (int o = 0; o < 9; o++) {
      l[o] += pw_b[o];
      mx = fmaxf(mx, l[o]);
    }
    float ssum = 0.f;
#pragma unroll
    for (int o = 0; o < 9; o++) {
      q[o] = expf(l[o] - mx);
      ssum += q[o];
    }
#pragma unroll
    for (int o = 0; o < 9; o++) q[o] = q[o] / ssum;

    // static clipped-neighbor columns (all indices compile-time under unroll)
    int colv[9];
#pragma unroll
    for (int o = 0; o < 9; o++) {
      int dy = o / 3 - 1, dx = o % 3 - 1;
      int ny = min(max(y + dy, 0), Hh - 1);
      int nx = min(max(x + dx, 0), Ww - 1);
      colv[o] = ny * Ww + nx;
    }
    // duplicate-accumulate + argmax, tie -> lowest column. For each o the
    // column value is built in ascending-o' order (matches scatter-add).
    float best = -1.f;
    int bcol = 1 << 30;
#pragma unroll
    for (int o = 0; o < 9; o++) {
      float v = 0.f;
#pragma unroll
      for (int oo = 0; oo < 9; oo++)
        v = (colv[oo] == colv[o]) ? v + q[oo] : v;
      if (v > best || (v == best && colv[o] < bcol)) {
        best = v;
        bcol = colv[o];
      }
    }
    ((int*)basef)[R0_OFF + n] = bcol;
    basef[P_OFF + n] = l[9];
  }
}

// ---------------------------------------------------------------------------
// K2' (fused cluster_topk + scores_plan): 6x pointer jumping + counts +
//     stable counting sort + top-256 (exact top_k ties) + scores + top-128 +
//     plan write — all in one 576-thread block per batch. Members, offsets,
//     ord/cnt and P all stay in LDS; no MEMB/OFFS/ORD/CNT global round-trip.
// ---------------------------------------------------------------------------
__global__ __launch_bounds__(576) void cluster_scores_plan_kernel(
    float* __restrict__ outb) {
  int b = blockIdx.x;
  int n = threadIdx.x;
  float* basef = batch_base(outb, b);
  int* base = (int*)basef;
  __shared__ int ra[Nn], rb[Nn], scnt[Nn], soff[Nn], smem[Nn];
  __shared__ float sp[Nn];
  __shared__ int s_ord[Kk], s_cnt[Kk], sel[Kk], s_out[Mm];
  __shared__ float ss[Kk];
  ra[n] = base[R0_OFF + n];
  sp[n] = basef[P_OFF + n];
  scnt[n] = 0;
  __syncthreads();
  for (int it = 0; it < 6; it++) {
    rb[n] = ra[ra[n]];
    __syncthreads();
    ra[n] = rb[n];
    __syncthreads();
  }
  int r = ra[n];
  atomicAdd(&scnt[r], 1);
  __syncthreads();

  // inclusive scan of scnt -> soff
  soff[n] = scnt[n];
  __syncthreads();
  for (int s = 1; s < Nn; s <<= 1) {
    int v = (n >= s) ? soff[n - s] : 0;
    __syncthreads();
    soff[n] += v;
    __syncthreads();
  }
  // stable counting sort into LDS member list
  int offr = soff[r] - scnt[r];
  int rk = 0;
  for (int m = 0; m < n; m++) rk += (ra[m] == r);
  smem[offr + rk] = n;

  // --- top-256 of counts (value desc, index asc), ascending-index output ---
  int cn = scnt[n];
  int rank = 0;
  for (int m = 0; m < Nn; m++) {
    int cm = scnt[m];
    rank += (cm > cn) || (cm == cn && m < n);
  }
  int sl = (rank < Kk) ? 1 : 0;
  rb[n] = sl;
  __syncthreads();
  for (int s = 1; s < Nn; s <<= 1) {
    int v = (n >= s) ? rb[n - s] : 0;
    __syncthreads();
    rb[n] += v;
    __syncthreads();
  }
  if (sl) {
    int pos = rb[n] - 1;
    s_ord[pos] = n;
    s_cnt[pos] = cn;
  }
  __syncthreads();  // smem + s_ord/s_cnt complete

  // --- scores (first 256 threads, one selected cluster each) ---
  if (n < Kk) {
    int idx = s_ord[n];
    int c = s_cnt[n];
    float s;
    if (c > 0) {
      int off = soff[idx] - scnt[idx];
      float sum = 0.f;
      for (int j = 0; j < c; j++) sum += sp[smem[off + j]];
      s = (sum / (float)c + basef[T_OFF]) * (1.0f / 32.0f);
    } else {
      s = -INFINITY;
    }
    ss[n] = s;
  }
  __syncthreads();

  // --- top-128 (value desc, index asc), ascending-index output ---
  if (n < Kk) {
    float vk = ss[n];
    int rank2 = 0;
    for (int m = 0; m < Kk; m++) {
      float vm = ss[m];
      rank2 += (vm > vk) || (vm == vk && m < n);
    }
    sel[n] = (rank2 < Mm) ? 1 : 0;
  }
  __syncthreads();
  if (n < Kk && sel[n]) {
    int pos = 0;
    for (int m = 0; m < n; m++) pos += sel[m];
    s_out[pos] = n;
  }
  __syncthreads();

  // --- plan: write [count, member ids...] into this batch's 128 rows ---
  int w9 = n >> 6, lane = n & 63;
  for (int kp = w9; kp < Mm; kp += 9) {
    int k = s_out[kp];
    int kidx = s_ord[k];
    int kc = s_cnt[k];
    int koff = soff[kidx] - scnt[kidx];
    int* row = base + kp * Dd;
    if (lane == 0) row[0] = kc;
    for (int j = lane; j < kc; j += 64) row[1 + j] = smem[koff + j];
  }
}

// ---------------------------------------------------------------------------
// K8: output. One block per output row; reads its OWN row's plan into LDS,
//     then overwrites the row with the cluster mean. float4 over d.
// ---------------------------------------------------------------------------
__global__ __launch_bounds__(256) void output_kernel(
    const float* __restrict__ tok2d, float* __restrict__ outb) {
  int blk = blockIdx.x;  // b*Mm + kp
  int b = blk / Mm;
  int tid = threadIdx.x;
  float* rowf = outb + (size_t)blk * Dd;
  int* rowi = (int*)rowf;
  __shared__ int s_c;
  __shared__ int s_m[Nn];
  if (tid == 0) s_c = rowi[0];
  __syncthreads();
  int c = s_c;
  for (int j = tid; j < c; j += 256) s_m[j] = rowi[1 + j];
  __syncthreads();
  const float* patch = tok2d + (size_t)b * TOKSTRIDE + Dd;
  int d0 = tid * 4;
  float4 acc = make_float4(0.f, 0.f, 0.f, 0.f);
  for (int j = 0; j < c; j++) {
    float4 rv = *(const float4*)(patch + (size_t)s_m[j] * Dd + d0);
    acc.x += rv.x; acc.y += rv.y; acc.z += rv.z; acc.w += rv.w;
  }
  float inv = 1.0f / (float)max(c, 1);
  *(float4*)(rowf + d0) =
      make_float4(acc.x * inv, acc.y * inv, acc.z * inv, acc.w * inv);
}

// ---------------------------------------------------------------------------
extern "C" void kernel_launch(void* const* d_in, const int* in_sizes, int n_in,
                              void* d_out, int out_size, void* d_ws,
                              size_t ws_size, hipStream_t stream) {
  const float* tok2d = (const float*)d_in[0];
  const float* dw_w = (const float*)d_in[1];
  const float* pw_w = (const float*)d_in[2];
  const float* pw_b = (const float*)d_in[3];
  const float* q_w = (const float*)d_in[4];
  const float* q_b = (const float*)d_in[5];
  const float* v_w = (const float*)d_in[6];
  const float* v_b = (const float*)d_in[7];
  float* out = (float*)d_out;
  (void)d_ws; (void)ws_size;  // d_ws intentionally unused

  // u/t first (affinity's fused p-dot needs u)
  qcls_kernel<<<dim3(Dd), dim3(256), 0, stream>>>(tok2d, q_w, q_b, out);
  u_t_kernel<<<dim3(32), dim3(256), 0, stream>>>(v_w, v_b, out);
  affinity_p_root_kernel<<<dim3(Bb * Hh * 3), dim3(256), 0, stream>>>(
      tok2d, dw_w, pw_w, pw_b, out);
  cluster_scores_plan_kernel<<<dim3(Bb), dim3(Nn), 0, stream>>>(out);
  output_kernel<<<dim3(Bb * Mm), dim3(256), 0, stream>>>(tok2d, out);
}

// Round 5
// 239.138 us; speedup vs baseline: 2.1915x; 2.1915x over previous
//
#include <hip/hip_runtime.h>
#include <math.h>

#define Hh 24
#define Ww 24
#define Nn 576
#define Dd 1024
#define Bb 32
#define Kk 256
#define Mm 128
#define TOKSTRIDE (577 * 1024)

// Per-batch scratch lives INSIDE d_out: batch b owns out[b*Mm*Dd .. (b+1)*Mm*Dd).
// Scratch is consumed (via LDS/regs) before the plan/output phases overwrite
// the rows. d_ws is NOT used.
#define R0_OFF 0       // roots0           : 576 int
#define P_OFF 2944     // p = patch.u      : 576 float
#define QC_OFF 3776    // qcls             : 1024 float
#define U_OFF 4800     // u = qcls.v_w     : 1024 float
#define T_OFF 5824     // t = qcls.v_b     : 1 float
#define UP_OFF 6144    // u partials       : 8*1024 float (ends 14336 < 131072)

__device__ __forceinline__ float* batch_base(float* out, int b) {
  return out + (size_t)b * Mm * Dd;
}

// Full-wave (64-lane) float sum via DPP — VALU pipe only, no LDS traffic.
// Canonical gfx9/CDNA sequence; result valid in lane 63.
__device__ __forceinline__ float wave_sum_dpp(float x) {
  int y;
  y = __builtin_amdgcn_update_dpp(0, __float_as_int(x), 0x111, 0xf, 0xf, true);
  x += __int_as_float(y);  // row_shr:1
  y = __builtin_amdgcn_update_dpp(0, __float_as_int(x), 0x112, 0xf, 0xf, true);
  x += __int_as_float(y);  // row_shr:2
  y = __builtin_amdgcn_update_dpp(0, __float_as_int(x), 0x114, 0xf, 0xf, true);
  x += __int_as_float(y);  // row_shr:4
  y = __builtin_amdgcn_update_dpp(0, __float_as_int(x), 0x118, 0xf, 0xf, true);
  x += __int_as_float(y);  // row_shr:8  -> lanes 15/31/47/63 hold row sums
  y = __builtin_amdgcn_update_dpp(0, __float_as_int(x), 0x142, 0xa, 0xf, true);
  x += __int_as_float(y);  // row_bcast:15 into rows 1,3
  y = __builtin_amdgcn_update_dpp(0, __float_as_int(x), 0x143, 0xc, 0xf, true);
  x += __int_as_float(y);  // row_bcast:31 into rows 2,3 -> lane 63 = total
  return x;
}

// 16-lane row sum via DPP (4 stages). Lanes 15/31/47/63 hold their row's sum.
__device__ __forceinline__ float row_sum_dpp(float x) {
  int y;
  y = __builtin_amdgcn_update_dpp(0, __float_as_int(x), 0x111, 0xf, 0xf, true);
  x += __int_as_float(y);  // row_shr:1
  y = __builtin_amdgcn_update_dpp(0, __float_as_int(x), 0x112, 0xf, 0xf, true);
  x += __int_as_float(y);  // row_shr:2
  y = __builtin_amdgcn_update_dpp(0, __float_as_int(x), 0x114, 0xf, 0xf, true);
  x += __int_as_float(y);  // row_shr:4
  y = __builtin_amdgcn_update_dpp(0, __float_as_int(x), 0x118, 0xf, 0xf, true);
  x += __int_as_float(y);  // row_shr:8
  return x;
}

// ---------------------------------------------------------------------------
// K4 (runs FIRST): qcls[b,dp] = cls[b]·q_w[dp,:] + q_b[dp]. One block per dp;
//     4 waves, each handles 8 batches (q_w row reused in regs).
// ---------------------------------------------------------------------------
__global__ __launch_bounds__(256) void qcls_kernel(
    const float* __restrict__ tok2d, const float* __restrict__ q_w,
    const float* __restrict__ q_b, float* __restrict__ outb) {
  int dp = blockIdx.x;
  int wave = threadIdx.x >> 6;
  int lane = threadIdx.x & 63;
  float4 qv[4];
#pragma unroll
  for (int i = 0; i < 4; i++)
    qv[i] = *(const float4*)(q_w + (size_t)dp * Dd + lane * 4 + 256 * i);
  float qb = q_b[dp];
  for (int bb = 0; bb < 8; bb++) {
    int b = wave * 8 + bb;
    const float* cls = tok2d + (size_t)b * TOKSTRIDE;
    float a = 0.f;
#pragma unroll
    for (int i = 0; i < 4; i++) {
      float4 cv = *(const float4*)(cls + lane * 4 + 256 * i);
      a += qv[i].x * cv.x + qv[i].y * cv.y + qv[i].z * cv.z + qv[i].w * cv.w;
    }
    a = wave_sum_dpp(a);
    if (lane == 63) batch_base(outb, b)[QC_OFF + dp] = a + qb;
  }
}

// ---------------------------------------------------------------------------
// K5: u partials: up[chunk][d] = sum_{dp in chunk} qcls[dp] * v_w[dp,d].
//     (round-3 proven version: 256 blocks, 128-deep loops)
// ---------------------------------------------------------------------------
__global__ __launch_bounds__(256) void u_part_kernel(const float* __restrict__ v_w,
                                                     float* __restrict__ outb) {
  int b = blockIdx.x >> 3;
  int chunk = blockIdx.x & 7;
  int tid = threadIdx.x;
  int d0 = tid * 4;
  float* basef = batch_base(outb, b);
  __shared__ float qs[128];
  if (tid < 128) qs[tid] = basef[QC_OFF + chunk * 128 + tid];
  __syncthreads();
  float4 a = make_float4(0.f, 0.f, 0.f, 0.f);
#pragma unroll 4
  for (int dpl = 0; dpl < 128; dpl++) {
    int dp = chunk * 128 + dpl;
    float4 vv = *(const float4*)(v_w + (size_t)dp * Dd + d0);
    float qq = qs[dpl];
    a.x += qq * vv.x; a.y += qq * vv.y; a.z += qq * vv.z; a.w += qq * vv.w;
  }
  *(float4*)(basef + UP_OFF + chunk * Dd + d0) = a;
}

// ---------------------------------------------------------------------------
// K6: combine u partials + t[b] = qcls[b]·v_b. One block per batch.
// ---------------------------------------------------------------------------
__global__ __launch_bounds__(256) void combine_ut_kernel(
    const float* __restrict__ v_b, float* __restrict__ outb) {
  int b = blockIdx.x;
  int tid = threadIdx.x;
  float* basef = batch_base(outb, b);
  int d0 = tid * 4;
  float4 s = make_float4(0.f, 0.f, 0.f, 0.f);
#pragma unroll
  for (int c = 0; c < 8; c++) {
    float4 v = *(const float4*)(basef + UP_OFF + c * Dd + d0);
    s.x += v.x; s.y += v.y; s.z += v.z; s.w += v.w;
  }
  *(float4*)(basef + U_OFF + d0) = s;

  float a = 0.f;
  for (int i = tid; i < Dd; i += 256) a += basef[QC_OFF + i] * v_b[i];
  __shared__ float sh[256];
  sh[tid] = a;
  __syncthreads();
  for (int st = 128; st > 0; st >>= 1) {
    if (tid < st) sh[tid] += sh[tid + st];
    __syncthreads();
  }
  if (tid == 0) basef[T_OFF] = sh[0];
}

// ---------------------------------------------------------------------------
// K1 v4 (round-3 proven, 53 µs): fused affinity + p. Block = (b, y, octet of
//     8 x's); 4 waves = 4 d-chunks of 256. All weights register-resident,
//     two-phase liveness split by sched_barrier; pw loaded after the conv.
//     __launch_bounds__(256,4) — the allocator's own 64-VGPR point (r3);
//     DO NOT force higher occupancy (r4: (256,8) -> 32 VGPR, 374 MB spill,
//     238 µs).
//     Reduction: 4-stage DPP 16-lane row sums -> 16 partials/(t,o) in padded
//     LDS; finalize 2 lanes x 4 waves, fixed r-order (bitwise stable).
//     XCD-bijective block swizzle (2304 = 8*288): contiguous (b,y) per XCD.
// ---------------------------------------------------------------------------
__global__ __launch_bounds__(256, 4) void affinity_p_root_kernel(
    const float* __restrict__ tok2d, const float* __restrict__ dw_w,
    const float* __restrict__ pw_w, const float* __restrict__ pw_b,
    float* __restrict__ outb) {
  int wave = threadIdx.x >> 6;  // d-chunk
  int lane = threadIdx.x & 63;
  // XCD-aware bijective swizzle: 2304 blocks = 8 XCDs * 288 contiguous ids.
  int blk = (blockIdx.x & 7) * (Bb * Hh * 3 / 8) + (blockIdx.x >> 3);
  int b = blk / (Hh * 3);
  int rem = blk % (Hh * 3);
  int y = rem / 3;
  int x0 = (rem % 3) * 8;
  int d0 = wave * 256 + lane * 4;
  const float* patch = tok2d + (size_t)b * TOKSTRIDE + Dd;  // skip cls token
  float* basef = batch_base(outb, b);

  // red layout: [t:0..7][r:0..15][o:0..9], linear idx = t*167 + r*10 + o.
  // 167 (odd, %32==7) pads the t-stride so finalizer lanes don't collide.
  __shared__ float red[8 * 167 + 8];

  // conv-phase registers: depthwise weights (36f) + u (4f)
  union { float4 v[9]; float f[36]; } w;
  const float4* dwp = (const float4*)(dw_w + (size_t)d0 * 9);
#pragma unroll
  for (int j = 0; j < 9; j++) w.v[j] = dwp[j];
  float4 u4 = *(const float4*)(basef + U_OFF + d0);

  // --- depthwise conv: sliding window over 3 rows x 10 cols ---
  float4 cc[8];
  float pacc[8];
#pragma unroll
  for (int t = 0; t < 8; t++) {
    cc[t] = make_float4(0.f, 0.f, 0.f, 0.f);
    pacc[t] = 0.f;
  }
#pragma unroll
  for (int ky = 0; ky < 3; ky++) {
    int yy = y + ky - 1;
    if (yy < 0 || yy >= Hh) continue;  // wave-uniform (zero padding)
    const float* prow = patch + (size_t)(yy * Ww) * Dd + d0;
    float4 wA = make_float4(0.f, 0.f, 0.f, 0.f);
    if (x0 > 0) wA = *(const float4*)(prow + (size_t)(x0 - 1) * Dd);
    float4 wB = *(const float4*)(prow + (size_t)x0 * Dd);
    int kA = ky * 3, kB = ky * 3 + 1, kC = ky * 3 + 2;
#pragma unroll
    for (int t = 0; t < 8; t++) {
      float4 wC = make_float4(0.f, 0.f, 0.f, 0.f);
      int xx = x0 + t + 1;
      if (xx < Ww) wC = *(const float4*)(prow + (size_t)xx * Dd);
      cc[t].x += wA.x * w.f[kA] + wB.x * w.f[kB] + wC.x * w.f[kC];
      cc[t].y += wA.y * w.f[9 + kA] + wB.y * w.f[9 + kB] + wC.y * w.f[9 + kC];
      cc[t].z += wA.z * w.f[18 + kA] + wB.z * w.f[18 + kB] + wC.z * w.f[18 + kC];
      cc[t].w += wA.w * w.f[27 + kA] + wB.w * w.f[27 + kB] + wC.w * w.f[27 + kC];
      if (ky == 1)  // middle row: wB is token t's center -> p partial
        pacc[t] = wB.x * u4.x + wB.y * u4.y + wB.z * u4.z + wB.w * u4.w;
      wA = wB;
      wB = wC;
    }
  }

  // fence: keep pw loads out of the conv region (two-phase VGPR liveness)
  __builtin_amdgcn_sched_barrier(0);

  // pointwise-phase registers: pw (36f); dw/u now dead
  float4 pw[9];
#pragma unroll
  for (int o = 0; o < 9; o++)
    pw[o] = *(const float4*)(pw_w + (size_t)o * Dd + d0);

  // --- per-token pointwise logits + 4-stage DPP row reduction ---
#pragma unroll
  for (int t = 0; t < 8; t++) {
    float acc[10];
#pragma unroll
    for (int o = 0; o < 9; o++) {
      acc[o] = cc[t].x * pw[o].x + cc[t].y * pw[o].y + cc[t].z * pw[o].z +
               cc[t].w * pw[o].w;
    }
    acc[9] = pacc[t];
#pragma unroll
    for (int o = 0; o < 10; o++) acc[o] = row_sum_dpp(acc[o]);
    if ((lane & 15) == 15) {
      int r = wave * 4 + (lane >> 4);
#pragma unroll
      for (int o = 0; o < 10; o++) red[t * 167 + r * 10 + o] = acc[o];
    }
  }
  __syncthreads();

  // --- finalize: 2 lanes per wave, token t = wave*2 + lane ---
  if (lane < 2) {
    int t = wave * 2 + lane;
    int x = x0 + t;
    int n = y * Ww + x;
    float l[10];
#pragma unroll
    for (int o = 0; o < 10; o++) l[o] = 0.f;
    for (int r = 0; r < 16; r++) {
#pragma unroll
      for (int o = 0; o < 10; o++) l[o] += red[t * 167 + r * 10 + o];
    }
    float q[9];
    float mx = -INFINITY;
#pragma unroll
    for (int o = 0; o < 9; o++) {
      l[o] += pw_b[o];
      mx = fmaxf(mx, l[o]);
    }
    float ssum = 0.f;
#pragma unroll
    for (int o = 0; o < 9; o++) {
      q[o] = expf(l[o] - mx);
      ssum += q[o];
    }
#pragma unroll
    for (int o = 0; o < 9; o++) q[o] = q[o] / ssum;

    // static clipped-neighbor columns (all indices compile-time under unroll)
    int colv[9];
#pragma unroll
    for (int o = 0; o < 9; o++) {
      int dy = o / 3 - 1, dx = o % 3 - 1;
      int ny = min(max(y + dy, 0), Hh - 1);
      int nx = min(max(x + dx, 0), Ww - 1);
      colv[o] = ny * Ww + nx;
    }
    // duplicate-accumulate + argmax, tie -> lowest column. For each o the
    // column value is built in ascending-o' order (matches scatter-add).
    float best = -1.f;
    int bcol = 1 << 30;
#pragma unroll
    for (int o = 0; o < 9; o++) {
      float v = 0.f;
#pragma unroll
      for (int oo = 0; oo < 9; oo++)
        v = (colv[oo] == colv[o]) ? v + q[oo] : v;
      if (v > best || (v == best && colv[o] < bcol)) {
        best = v;
        bcol = colv[o];
      }
    }
    ((int*)basef)[R0_OFF + n] = bcol;
    basef[P_OFF + n] = l[9];
  }
}

// ---------------------------------------------------------------------------
// K2' (fused cluster_topk + scores_plan): 6x pointer jumping + counts +
//     stable counting sort + top-256 (exact top_k ties) + scores + top-128 +
//     plan write — all in one 576-thread block per batch. Members, offsets,
//     ord/cnt and P all stay in LDS; no MEMB/OFFS/ORD/CNT global round-trip.
//     (verified correct in round 4; this round isolates its perf A/B)
// ---------------------------------------------------------------------------
__global__ __launch_bounds__(576) void cluster_scores_plan_kernel(
    float* __restrict__ outb) {
  int b = blockIdx.x;
  int n = threadIdx.x;
  float* basef = batch_base(outb, b);
  int* base = (int*)basef;
  __shared__ int ra[Nn], rb[Nn], scnt[Nn], soff[Nn], smem[Nn];
  __shared__ float sp[Nn];
  __shared__ int s_ord[Kk], s_cnt[Kk], sel[Kk], s_out[Mm];
  __shared__ float ss[Kk];
  ra[n] = base[R0_OFF + n];
  sp[n] = basef[P_OFF + n];
  scnt[n] = 0;
  __syncthreads();
  for (int it = 0; it < 6; it++) {
    rb[n] = ra[ra[n]];
    __syncthreads();
    ra[n] = rb[n];
    __syncthreads();
  }
  int r = ra[n];
  atomicAdd(&scnt[r], 1);
  __syncthreads();

  // inclusive scan of scnt -> soff
  soff[n] = scnt[n];
  __syncthreads();
  for (int s = 1; s < Nn; s <<= 1) {
    int v = (n >= s) ? soff[n - s] : 0;
    __syncthreads();
    soff[n] += v;
    __syncthreads();
  }
  // stable counting sort into LDS member list
  int offr = soff[r] - scnt[r];
  int rk = 0;
  for (int m = 0; m < n; m++) rk += (ra[m] == r);
  smem[offr + rk] = n;

  // --- top-256 of counts (value desc, index asc), ascending-index output ---
  int cn = scnt[n];
  int rank = 0;
  for (int m = 0; m < Nn; m++) {
    int cm = scnt[m];
    rank += (cm > cn) || (cm == cn && m < n);
  }
  int sl = (rank < Kk) ? 1 : 0;
  rb[n] = sl;
  __syncthreads();
  for (int s = 1; s < Nn; s <<= 1) {
    int v = (n >= s) ? rb[n - s] : 0;
    __syncthreads();
    rb[n] += v;
    __syncthreads();
  }
  if (sl) {
    int pos = rb[n] - 1;
    s_ord[pos] = n;
    s_cnt[pos] = cn;
  }
  __syncthreads();  // smem + s_ord/s_cnt complete

  // --- scores (first 256 threads, one selected cluster each) ---
  if (n < Kk) {
    int idx = s_ord[n];
    int c = s_cnt[n];
    float s;
    if (c > 0) {
      int off = soff[idx] - scnt[idx];
      float sum = 0.f;
      for (int j = 0; j < c; j++) sum += sp[smem[off + j]];
      s = (sum / (float)c + basef[T_OFF]) * (1.0f / 32.0f);
    } else {
      s = -INFINITY;
    }
    ss[n] = s;
  }
  __syncthreads();

  // --- top-128 (value desc, index asc), ascending-index output ---
  if (n < Kk) {
    float vk = ss[n];
    int rank2 = 0;
    for (int m = 0; m < Kk; m++) {
      float vm = ss[m];
      rank2 += (vm > vk) || (vm == vk && m < n);
    }
    sel[n] = (rank2 < Mm) ? 1 : 0;
  }
  __syncthreads();
  if (n < Kk && sel[n]) {
    int pos = 0;
    for (int m = 0; m < n; m++) pos += sel[m];
    s_out[pos] = n;
  }
  __syncthreads();

  // --- plan: write [count, member ids...] into this batch's 128 rows ---
  int w9 = n >> 6, lane = n & 63;
  for (int kp = w9; kp < Mm; kp += 9) {
    int k = s_out[kp];
    int kidx = s_ord[k];
    int kc = s_cnt[k];
    int koff = soff[kidx] - scnt[kidx];
    int* row = base + kp * Dd;
    if (lane == 0) row[0] = kc;
    for (int j = lane; j < kc; j += 64) row[1 + j] = smem[koff + j];
  }
}

// ---------------------------------------------------------------------------
// K8: output. One block per output row; reads its OWN row's plan into LDS,
//     then overwrites the row with the cluster mean. float4 over d.
// ---------------------------------------------------------------------------
__global__ __launch_bounds__(256) void output_kernel(
    const float* __restrict__ tok2d, float* __restrict__ outb) {
  int blk = blockIdx.x;  // b*Mm + kp
  int b = blk / Mm;
  int tid = threadIdx.x;
  float* rowf = outb + (size_t)blk * Dd;
  int* rowi = (int*)rowf;
  __shared__ int s_c;
  __shared__ int s_m[Nn];
  if (tid == 0) s_c = rowi[0];
  __syncthreads();
  int c = s_c;
  for (int j = tid; j < c; j += 256) s_m[j] = rowi[1 + j];
  __syncthreads();
  const float* patch = tok2d + (size_t)b * TOKSTRIDE + Dd;
  int d0 = tid * 4;
  float4 acc = make_float4(0.f, 0.f, 0.f, 0.f);
  for (int j = 0; j < c; j++) {
    float4 rv = *(const float4*)(patch + (size_t)s_m[j] * Dd + d0);
    acc.x += rv.x; acc.y += rv.y; acc.z += rv.z; acc.w += rv.w;
  }
  float inv = 1.0f / (float)max(c, 1);
  *(float4*)(rowf + d0) =
      make_float4(acc.x * inv, acc.y * inv, acc.z * inv, acc.w * inv);
}

// ---------------------------------------------------------------------------
extern "C" void kernel_launch(void* const* d_in, const int* in_sizes, int n_in,
                              void* d_out, int out_size, void* d_ws,
                              size_t ws_size, hipStream_t stream) {
  const float* tok2d = (const float*)d_in[0];
  const float* dw_w = (const float*)d_in[1];
  const float* pw_w = (const float*)d_in[2];
  const float* pw_b = (const float*)d_in[3];
  const float* q_w = (const float*)d_in[4];
  const float* q_b = (const float*)d_in[5];
  const float* v_w = (const float*)d_in[6];
  const float* v_b = (const float*)d_in[7];
  float* out = (float*)d_out;
  (void)d_ws; (void)ws_size;  // d_ws intentionally unused

  // u/t first (affinity's fused p-dot needs u)
  qcls_kernel<<<dim3(Dd), dim3(256), 0, stream>>>(tok2d, q_w, q_b, out);
  u_part_kernel<<<dim3(Bb * 8), dim3(256), 0, stream>>>(v_w, out);
  combine_ut_kernel<<<dim3(Bb), dim3(256), 0, stream>>>(v_b, out);
  affinity_p_root_kernel<<<dim3(Bb * Hh * 3), dim3(256), 0, stream>>>(
      tok2d, dw_w, pw_w, pw_b, out);
  cluster_scores_plan_kernel<<<dim3(Bb), dim3(Nn), 0, stream>>>(out);
  output_kernel<<<dim3(Bb * Mm), dim3(256), 0, stream>>>(tok2d, out);
}

// Round 6
// 232.789 us; speedup vs baseline: 2.2512x; 1.0273x over previous
//
#include <hip/hip_runtime.h>
#include <math.h>

#define Hh 24
#define Ww 24
#define Nn 576
#define Dd 1024
#define Bb 32
#define Kk 256
#define Mm 128
#define TOKSTRIDE (577 * 1024)

// Per-batch scratch lives INSIDE d_out: batch b owns out[b*Mm*Dd .. (b+1)*Mm*Dd).
// Scratch is consumed (via LDS/regs) before the plan/output phases overwrite
// the rows. d_ws is NOT used.
#define R0_OFF 0       // roots0           : 576 int
#define P_OFF 2944     // p = patch.u      : 576 float
#define QC_OFF 3776    // qcls             : 1024 float
#define U_OFF 4800     // u = qcls.v_w     : 1024 float
#define T_OFF 5824     // t = qcls.v_b     : 1 float

__device__ __forceinline__ float* batch_base(float* out, int b) {
  return out + (size_t)b * Mm * Dd;
}

// Full-wave (64-lane) float sum via DPP — VALU pipe only, no LDS traffic.
// Canonical gfx9/CDNA sequence; result valid in lane 63.
__device__ __forceinline__ float wave_sum_dpp(float x) {
  int y;
  y = __builtin_amdgcn_update_dpp(0, __float_as_int(x), 0x111, 0xf, 0xf, true);
  x += __int_as_float(y);  // row_shr:1
  y = __builtin_amdgcn_update_dpp(0, __float_as_int(x), 0x112, 0xf, 0xf, true);
  x += __int_as_float(y);  // row_shr:2
  y = __builtin_amdgcn_update_dpp(0, __float_as_int(x), 0x114, 0xf, 0xf, true);
  x += __int_as_float(y);  // row_shr:4
  y = __builtin_amdgcn_update_dpp(0, __float_as_int(x), 0x118, 0xf, 0xf, true);
  x += __int_as_float(y);  // row_shr:8  -> lanes 15/31/47/63 hold row sums
  y = __builtin_amdgcn_update_dpp(0, __float_as_int(x), 0x142, 0xa, 0xf, true);
  x += __int_as_float(y);  // row_bcast:15 into rows 1,3
  y = __builtin_amdgcn_update_dpp(0, __float_as_int(x), 0x143, 0xc, 0xf, true);
  x += __int_as_float(y);  // row_bcast:31 into rows 2,3 -> lane 63 = total
  return x;
}

// 16-lane row sum via DPP (4 stages). Lanes 15/31/47/63 hold their row's sum.
__device__ __forceinline__ float row_sum_dpp(float x) {
  int y;
  y = __builtin_amdgcn_update_dpp(0, __float_as_int(x), 0x111, 0xf, 0xf, true);
  x += __int_as_float(y);  // row_shr:1
  y = __builtin_amdgcn_update_dpp(0, __float_as_int(x), 0x112, 0xf, 0xf, true);
  x += __int_as_float(y);  // row_shr:2
  y = __builtin_amdgcn_update_dpp(0, __float_as_int(x), 0x114, 0xf, 0xf, true);
  x += __int_as_float(y);  // row_shr:4
  y = __builtin_amdgcn_update_dpp(0, __float_as_int(x), 0x118, 0xf, 0xf, true);
  x += __int_as_float(y);  // row_shr:8
  return x;
}

// ---------------------------------------------------------------------------
// K4 (runs FIRST): qcls[b,dp] = cls[b]·q_w[dp,:] + q_b[dp]. One block per dp;
//     4 waves, each handles 8 batches (q_w row reused in regs).
// ---------------------------------------------------------------------------
__global__ __launch_bounds__(256) void qcls_kernel(
    const float* __restrict__ tok2d, const float* __restrict__ q_w,
    const float* __restrict__ q_b, float* __restrict__ outb) {
  int dp = blockIdx.x;
  int wave = threadIdx.x >> 6;
  int lane = threadIdx.x & 63;
  float4 qv[4];
#pragma unroll
  for (int i = 0; i < 4; i++)
    qv[i] = *(const float4*)(q_w + (size_t)dp * Dd + lane * 4 + 256 * i);
  float qb = q_b[dp];
  for (int bb = 0; bb < 8; bb++) {
    int b = wave * 8 + bb;
    const float* cls = tok2d + (size_t)b * TOKSTRIDE;
    float a = 0.f;
#pragma unroll
    for (int i = 0; i < 4; i++) {
      float4 cv = *(const float4*)(cls + lane * 4 + 256 * i);
      a += qv[i].x * cv.x + qv[i].y * cv.y + qv[i].z * cv.z + qv[i].w * cv.w;
    }
    a = wave_sum_dpp(a);
    if (lane == 63) batch_base(outb, b)[QC_OFF + dp] = a + qb;
  }
}

// ---------------------------------------------------------------------------
// K5'' (fused u_part + combine_ut, full-chip): grid 256 = (b:32) x (slice:8).
//     Block (b,s): u[b][s*128 .. s*128+127] = sum_dp qcls[b][dp]*v_w[dp][d].
//     Threads = 8 dp-groups x 32 d-lanes (float4). Each group g accumulates
//     over dp in [g*128,(g+1)*128) ascending — exactly the old UP[c] chunk —
//     then 32 lanes left-fold the 8 partials in ascending-g order — exactly
//     the old combine loop. Bitwise-identical u; one launch fewer; no UP
//     global round-trip. t replicated verbatim in slice-0 blocks.
// ---------------------------------------------------------------------------
__global__ __launch_bounds__(256) void u_t_kernel(const float* __restrict__ v_w,
                                                  const float* __restrict__ v_b,
                                                  float* __restrict__ outb) {
  int b = blockIdx.x >> 3;
  int s = blockIdx.x & 7;
  int tid = threadIdx.x;
  int dl = tid & 31;   // d float4-lane within slice
  int g = tid >> 5;    // dp-group (== old chunk c)
  float* basef = batch_base(outb, b);
  __shared__ float qs[Dd];
  __shared__ float4 part[8][32];
  __shared__ float sh[256];
  for (int i = tid; i < Dd; i += 256) qs[i] = basef[QC_OFF + i];
  __syncthreads();
  int d0 = s * 128 + dl * 4;
  float4 a = make_float4(0.f, 0.f, 0.f, 0.f);
#pragma unroll 4
  for (int dpl = 0; dpl < 128; dpl++) {
    int dp = g * 128 + dpl;
    float4 vv = *(const float4*)(v_w + (size_t)dp * Dd + d0);
    float qq = qs[dp];
    a.x += qq * vv.x; a.y += qq * vv.y; a.z += qq * vv.z; a.w += qq * vv.w;
  }
  part[g][dl] = a;
  __syncthreads();
  if (tid < 32) {
    // left-fold ascending g — identical FP order to combine_ut's c-loop
    float4 u = make_float4(0.f, 0.f, 0.f, 0.f);
#pragma unroll
    for (int c = 0; c < 8; c++) {
      float4 v = part[c][tid];
      u.x += v.x; u.y += v.y; u.z += v.z; u.w += v.w;
    }
    *(float4*)(basef + U_OFF + s * 128 + tid * 4) = u;
  }

  if (s == 0) {  // t, verbatim combine_ut pattern (block-uniform branch)
    float aa = 0.f;
    for (int i = tid; i < Dd; i += 256) aa += qs[i] * v_b[i];
    sh[tid] = aa;
    __syncthreads();
    for (int st = 128; st > 0; st >>= 1) {
      if (tid < st) sh[tid] += sh[tid + st];
      __syncthreads();
    }
    if (tid == 0) basef[T_OFF] = sh[0];
  }
}

// ---------------------------------------------------------------------------
// K1 v6: fused affinity + p. Block = (b, y, octet of 8 x's); 4 waves = 4
//     d-chunks of 256.
//     v6 change: conv loads the full 10-wide row window into wrow[10] FIRST
//     (10 independent float4 loads issued back-to-back), then the 8-token
//     FMA sweep runs from registers. Same expression shape per token
//     (wA*kA + wB*kB + wC*kC) -> bitwise-identical; the sliding-window
//     load-use serialization is gone.
//     __launch_bounds__(256,3): RELAXES the VGPR cap to ~170 so wrow(40)+
//     cc(32)+dw(36) fit without the r3 8 B/thread spill. (r4 lesson: never
//     TIGHTEN the cap — (256,8) forced 32 VGPR and 374 MB of spill.)
//     12 waves/CU instead of 16, traded for ~2.5x more loads in flight.
//     Watch: VGPR>170 or WRITE_SIZE>=4 MB means wrow spilled -> revert.
//     Reduction: 4-stage DPP 16-lane row sums -> 16 partials/(t,o) in padded
//     LDS; finalize 2 lanes x 4 waves, fixed r-order (bitwise stable).
//     XCD-bijective block swizzle (2304 = 8*288): contiguous (b,y) per XCD.
// ---------------------------------------------------------------------------
__global__ __launch_bounds__(256, 3) void affinity_p_root_kernel(
    const float* __restrict__ tok2d, const float* __restrict__ dw_w,
    const float* __restrict__ pw_w, const float* __restrict__ pw_b,
    float* __restrict__ outb) {
  int wave = threadIdx.x >> 6;  // d-chunk
  int lane = threadIdx.x & 63;
  // XCD-aware bijective swizzle: 2304 blocks = 8 XCDs * 288 contiguous ids.
  int blk = (blockIdx.x & 7) * (Bb * Hh * 3 / 8) + (blockIdx.x >> 3);
  int b = blk / (Hh * 3);
  int rem = blk % (Hh * 3);
  int y = rem / 3;
  int x0 = (rem % 3) * 8;
  int d0 = wave * 256 + lane * 4;
  const float* patch = tok2d + (size_t)b * TOKSTRIDE + Dd;  // skip cls token
  float* basef = batch_base(outb, b);

  // red layout: [t:0..7][r:0..15][o:0..9], linear idx = t*167 + r*10 + o.
  // 167 (odd, %32==7) pads the t-stride so finalizer lanes don't collide.
  __shared__ float red[8 * 167 + 8];

  // conv-phase registers: depthwise weights (36f) + u (4f)
  union { float4 v[9]; float f[36]; } w;
  const float4* dwp = (const float4*)(dw_w + (size_t)d0 * 9);
#pragma unroll
  for (int j = 0; j < 9; j++) w.v[j] = dwp[j];
  float4 u4 = *(const float4*)(basef + U_OFF + d0);

  // --- depthwise conv: per input row, batch-load 10-wide window, then FMA ---
  float4 cc[8];
  float pacc[8];
#pragma unroll
  for (int t = 0; t < 8; t++) {
    cc[t] = make_float4(0.f, 0.f, 0.f, 0.f);
    pacc[t] = 0.f;
  }
#pragma unroll
  for (int ky = 0; ky < 3; ky++) {
    int yy = y + ky - 1;
    if (yy < 0 || yy >= Hh) continue;  // wave-uniform (zero padding)
    const float* prow = patch + (size_t)(yy * Ww) * Dd + d0;
    float4 wrow[10];  // cols x0-1 .. x0+8; all indices compile-time (regs)
    wrow[0] = make_float4(0.f, 0.f, 0.f, 0.f);
    if (x0 > 0) wrow[0] = *(const float4*)(prow + (size_t)(x0 - 1) * Dd);
#pragma unroll
    for (int j = 1; j < 9; j++)
      wrow[j] = *(const float4*)(prow + (size_t)(x0 - 1 + j) * Dd);
    wrow[9] = make_float4(0.f, 0.f, 0.f, 0.f);
    if (x0 + 8 < Ww) wrow[9] = *(const float4*)(prow + (size_t)(x0 + 8) * Dd);
    int kA = ky * 3, kB = ky * 3 + 1, kC = ky * 3 + 2;
#pragma unroll
    for (int t = 0; t < 8; t++) {
      cc[t].x += wrow[t].x * w.f[kA] + wrow[t + 1].x * w.f[kB] +
                 wrow[t + 2].x * w.f[kC];
      cc[t].y += wrow[t].y * w.f[9 + kA] + wrow[t + 1].y * w.f[9 + kB] +
                 wrow[t + 2].y * w.f[9 + kC];
      cc[t].z += wrow[t].z * w.f[18 + kA] + wrow[t + 1].z * w.f[18 + kB] +
                 wrow[t + 2].z * w.f[18 + kC];
      cc[t].w += wrow[t].w * w.f[27 + kA] + wrow[t + 1].w * w.f[27 + kB] +
                 wrow[t + 2].w * w.f[27 + kC];
      if (ky == 1)  // middle row: wrow[t+1] is token t's center -> p partial
        pacc[t] = wrow[t + 1].x * u4.x + wrow[t + 1].y * u4.y +
                  wrow[t + 1].z * u4.z + wrow[t + 1].w * u4.w;
    }
  }

  // fence: keep pw loads out of the conv region (two-phase VGPR liveness)
  __builtin_amdgcn_sched_barrier(0);

  // pointwise-phase registers: pw (36f); dw/u now dead
  float4 pw[9];
#pragma unroll
  for (int o = 0; o < 9; o++)
    pw[o] = *(const float4*)(pw_w + (size_t)o * Dd + d0);

  // --- per-token pointwise logits + 4-stage DPP row reduction ---
#pragma unroll
  for (int t = 0; t < 8; t++) {
    float acc[10];
#pragma unroll
    for (int o = 0; o < 9; o++) {
      acc[o] = cc[t].x * pw[o].x + cc[t].y * pw[o].y + cc[t].z * pw[o].z +
               cc[t].w * pw[o].w;
    }
    acc[9] = pacc[t];
#pragma unroll
    for (int o = 0; o < 10; o++) acc[o] = row_sum_dpp(acc[o]);
    if ((lane & 15) == 15) {
      int r = wave * 4 + (lane >> 4);
#pragma unroll
      for (int o = 0; o < 10; o++) red[t * 167 + r * 10 + o] = acc[o];
    }
  }
  __syncthreads();

  // --- finalize: 2 lanes per wave, token t = wave*2 + lane ---
  if (lane < 2) {
    int t = wave * 2 + lane;
    int x = x0 + t;
    int n = y * Ww + x;
    float l[10];
#pragma unroll
    for (int o = 0; o < 10; o++) l[o] = 0.f;
    for (int r = 0; r < 16; r++) {
#pragma unroll
      for (int o = 0; o < 10; o++) l[o] += red[t * 167 + r * 10 + o];
    }
    float q[9];
    float mx = -INFINITY;
#pragma unroll
    for (int o = 0; o < 9; o++) {
      l[o] += pw_b[o];
      mx = fmaxf(mx, l[o]);
    }
    float ssum = 0.f;
#pragma unroll
    for (int o = 0; o < 9; o++) {
      q[o] = expf(l[o] - mx);
      ssum += q[o];
    }
#pragma unroll
    for (int o = 0; o < 9; o++) q[o] = q[o] / ssum;

    // static clipped-neighbor columns (all indices compile-time under unroll)
    int colv[9];
#pragma unroll
    for (int o = 0; o < 9; o++) {
      int dy = o / 3 - 1, dx = o % 3 - 1;
      int ny = min(max(y + dy, 0), Hh - 1);
      int nx = min(max(x + dx, 0), Ww - 1);
      colv[o] = ny * Ww + nx;
    }
    // duplicate-accumulate + argmax, tie -> lowest column. For each o the
    // column value is built in ascending-o' order (matches scatter-add).
    float best = -1.f;
    int bcol = 1 << 30;
#pragma unroll
    for (int o = 0; o < 9; o++) {
      float v = 0.f;
#pragma unroll
      for (int oo = 0; oo < 9; oo++)
        v = (colv[oo] == colv[o]) ? v + q[oo] : v;
      if (v > best || (v == best && colv[o] < bcol)) {
        best = v;
        bcol = colv[o];
      }
    }
    ((int*)basef)[R0_OFF + n] = bcol;
    basef[P_OFF + n] = l[9];
  }
}

// ---------------------------------------------------------------------------
// K2' (fused cluster_topk + scores_plan): 6x pointer jumping + counts +
//     stable counting sort + top-256 (exact top_k ties) + scores + top-128 +
//     plan write — all in one 576-thread block per batch. Members, offsets,
//     ord/cnt and P all stay in LDS; no MEMB/OFFS/ORD/CNT global round-trip.
// ---------------------------------------------------------------------------
__global__ __launch_bounds__(576) void cluster_scores_plan_kernel(
    float* __restrict__ outb) {
  int b = blockIdx.x;
  int n = threadIdx.x;
  float* basef = batch_base(outb, b);
  int* base = (int*)basef;
  __shared__ int ra[Nn], rb[Nn], scnt[Nn], soff[Nn], smem[Nn];
  __shared__ float sp[Nn];
  __shared__ int s_ord[Kk], s_cnt[Kk], sel[Kk], s_out[Mm];
  __shared__ float ss[Kk];
  ra[n] = base[R0_OFF + n];
  sp[n] = basef[P_OFF + n];
  scnt[n] = 0;
  __syncthreads();
  for (int it = 0; it < 6; it++) {
    rb[n] = ra[ra[n]];
    __syncthreads();
    ra[n] = rb[n];
    __syncthreads();
  }
  int r = ra[n];
  atomicAdd(&scnt[r], 1);
  __syncthreads();

  // inclusive scan of scnt -> soff
  soff[n] = scnt[n];
  __syncthreads();
  for (int s = 1; s < Nn; s <<= 1) {
    int v = (n >= s) ? soff[n - s] : 0;
    __syncthreads();
    soff[n] += v;
    __syncthreads();
  }
  // stable counting sort into LDS member list
  int offr = soff[r] - scnt[r];
  int rk = 0;
  for (int m = 0; m < n; m++) rk += (ra[m] == r);
  smem[offr + rk] = n;

  // --- top-256 of counts (value desc, index asc), ascending-index output ---
  int cn = scnt[n];
  int rank = 0;
  for (int m = 0; m < Nn; m++) {
    int cm = scnt[m];
    rank += (cm > cn) || (cm == cn && m < n);
  }
  int sl = (rank < Kk) ? 1 : 0;
  rb[n] = sl;
  __syncthreads();
  for (int s = 1; s < Nn; s <<= 1) {
    int v = (n >= s) ? rb[n - s] : 0;
    __syncthreads();
    rb[n] += v;
    __syncthreads();
  }
  if (sl) {
    int pos = rb[n] - 1;
    s_ord[pos] = n;
    s_cnt[pos] = cn;
  }
  __syncthreads();  // smem + s_ord/s_cnt complete

  // --- scores (first 256 threads, one selected cluster each) ---
  if (n < Kk) {
    int idx = s_ord[n];
    int c = s_cnt[n];
    float s;
    if (c > 0) {
      int off = soff[idx] - scnt[idx];
      float sum = 0.f;
      for (int j = 0; j < c; j++) sum += sp[smem[off + j]];
      s = (sum / (float)c + basef[T_OFF]) * (1.0f / 32.0f);
    } else {
      s = -INFINITY;
    }
    ss[n] = s;
  }
  __syncthreads();

  // --- top-128 (value desc, index asc), ascending-index output ---
  if (n < Kk) {
    float vk = ss[n];
    int rank2 = 0;
    for (int m = 0; m < Kk; m++) {
      float vm = ss[m];
      rank2 += (vm > vk) || (vm == vk && m < n);
    }
    sel[n] = (rank2 < Mm) ? 1 : 0;
  }
  __syncthreads();
  if (n < Kk && sel[n]) {
    int pos = 0;
    for (int m = 0; m < n; m++) pos += sel[m];
    s_out[pos] = n;
  }
  __syncthreads();

  // --- plan: write [count, member ids...] into this batch's 128 rows ---
  int w9 = n >> 6, lane = n & 63;
  for (int kp = w9; kp < Mm; kp += 9) {
    int k = s_out[kp];
    int kidx = s_ord[k];
    int kc = s_cnt[k];
    int koff = soff[kidx] - scnt[kidx];
    int* row = base + kp * Dd;
    if (lane == 0) row[0] = kc;
    for (int j = lane; j < kc; j += 64) row[1 + j] = smem[koff + j];
  }
}

// ---------------------------------------------------------------------------
// K8: output. One block per output row; reads its OWN row's plan into LDS,
//     then overwrites the row with the cluster mean. float4 over d.
// ---------------------------------------------------------------------------
__global__ __launch_bounds__(256) void output_kernel(
    const float* __restrict__ tok2d, float* __restrict__ outb) {
  int blk = blockIdx.x;  // b*Mm + kp
  int b = blk / Mm;
  int tid = threadIdx.x;
  float* rowf = outb + (size_t)blk * Dd;
  int* rowi = (int*)rowf;
  __shared__ int s_c;
  __shared__ int s_m[Nn];
  if (tid == 0) s_c = rowi[0];
  __syncthreads();
  int c = s_c;
  for (int j = tid; j < c; j += 256) s_m[j] = rowi[1 + j];
  __syncthreads();
  const float* patch = tok2d + (size_t)b * TOKSTRIDE + Dd;
  int d0 = tid * 4;
  float4 acc = make_float4(0.f, 0.f, 0.f, 0.f);
  for (int j = 0; j < c; j++) {
    float4 rv = *(const float4*)(patch + (size_t)s_m[j] * Dd + d0);
    acc.x += rv.x; acc.y += rv.y; acc.z += rv.z; acc.w += rv.w;
  }
  float inv = 1.0f / (float)max(c, 1);
  *(float4*)(rowf + d0) =
      make_float4(acc.x * inv, acc.y * inv, acc.z * inv, acc.w * inv);
}

// ---------------------------------------------------------------------------
extern "C" void kernel_launch(void* const* d_in, const int* in_sizes, int n_in,
                              void* d_out, int out_size, void* d_ws,
                              size_t ws_size, hipStream_t stream) {
  const float* tok2d = (const float*)d_in[0];
  const float* dw_w = (const float*)d_in[1];
  const float* pw_w = (const float*)d_in[2];
  const float* pw_b = (const float*)d_in[3];
  const float* q_w = (const float*)d_in[4];
  const float* q_b = (const float*)d_in[5];
  const float* v_w = (const float*)d_in[6];
  const float* v_b = (const float*)d_in[7];
  float* out = (float*)d_out;
  (void)d_ws; (void)ws_size;  // d_ws intentionally unused

  // u/t first (affinity's fused p-dot needs u)
  qcls_kernel<<<dim3(Dd), dim3(256), 0, stream>>>(tok2d, q_w, q_b, out);
  u_t_kernel<<<dim3(Bb * 8), dim3(256), 0, stream>>>(v_w, v_b, out);
  affinity_p_root_kernel<<<dim3(Bb * Hh * 3), dim3(256), 0, stream>>>(
      tok2d, dw_w, pw_w, pw_b, out);
  cluster_scores_plan_kernel<<<dim3(Bb), dim3(Nn), 0, stream>>>(out);
  output_kernel<<<dim3(Bb * Mm), dim3(256), 0, stream>>>(tok2d, out);
}